// Round 1
// baseline (220.211 us; speedup 1.0000x reference)
//
#include <hip/hip_runtime.h>
#include <math.h>

// CropRoi: adaptive max-pool3d of per-proposal crops.
// f:         (B=2, C=128, 32, 64, 64) float32
// proposals: (N=32, 8) float32 = [b, score, cz, cy, cx, sz, sy, sx]
// out:       (N=32, C=128, 7, 7, 7) float32
//
// Semantics copied from the JAX reference:
//   c0 = max(floor((center - side/2)/4), 0)
//   c1 = min(ceil ((center + side/2)/4), feat_dim)
//   L  = c1 - c0
//   window i: [c0 + i*L//7, c0 + ceil((i+1)*L/7))   (empty window -> -inf)

#define POOL_S 7
constexpr int C_CH = 128;
constexpr int FD = 32, FH = 64, FW = 64;
constexpr int OUT_PER_N = C_CH * POOL_S * POOL_S * POOL_S;   // 43904
constexpr int TOTAL = 32 * OUT_PER_N;                        // 1404928

__global__ __launch_bounds__(256) void crop_roi_kernel(
    const float* __restrict__ f,
    const float* __restrict__ proposals,
    float* __restrict__ out)
{
    int tid = blockIdx.x * blockDim.x + threadIdx.x;
    if (tid >= TOTAL) return;

    int ix = tid % 7;
    int iy = (tid / 7) % 7;
    int iz = (tid / 49) % 7;
    int c  = (tid / 343) % C_CH;
    int n  = tid / OUT_PER_N;

    const float* p = proposals + n * 8;
    int   b  = (int)p[0];
    float cz = p[2], cy = p[3], cx = p[4];
    float sz = p[5], sy = p[6], sx = p[7];

    // exact match to reference: /SCALE == *0.25f (both exact in fp32)
    int c0z = max((int)floorf((cz - sz * 0.5f) * 0.25f), 0);
    int c0y = max((int)floorf((cy - sy * 0.5f) * 0.25f), 0);
    int c0x = max((int)floorf((cx - sx * 0.5f) * 0.25f), 0);
    int c1z = min((int)ceilf((cz + sz * 0.5f) * 0.25f), FD);
    int c1y = min((int)ceilf((cy + sy * 0.5f) * 0.25f), FH);
    int c1x = min((int)ceilf((cx + sx * 0.5f) * 0.25f), FW);
    int Lz = c1z - c0z, Ly = c1y - c0y, Lx = c1x - c0x;

    int z0 = c0z + (iz * Lz) / 7, z1 = c0z + ((iz + 1) * Lz + 6) / 7;
    int y0 = c0y + (iy * Ly) / 7, y1 = c0y + ((iy + 1) * Ly + 6) / 7;
    int x0 = c0x + (ix * Lx) / 7, x1 = c0x + ((ix + 1) * Lx + 6) / 7;

    const float* fb = f + (size_t)(b * C_CH + c) * (FD * FH * FW);

    float m = -INFINITY;
    for (int z = z0; z < z1; ++z) {
        const float* fz = fb + z * (FH * FW);
        for (int y = y0; y < y1; ++y) {
            const float* fy = fz + y * FW;
            for (int x = x0; x < x1; ++x) {
                m = fmaxf(m, fy[x]);
            }
        }
    }
    out[tid] = m;
}

extern "C" void kernel_launch(void* const* d_in, const int* in_sizes, int n_in,
                              void* d_out, int out_size, void* d_ws, size_t ws_size,
                              hipStream_t stream) {
    const float* f         = (const float*)d_in[0];
    // d_in[1] = inputs (zeros) — only used for shape in the reference; unused here.
    const float* proposals = (const float*)d_in[2];
    float* out             = (float*)d_out;

    const int block = 256;
    const int grid  = (TOTAL + block - 1) / block;  // 5489 blocks
    crop_roi_kernel<<<grid, block, 0, stream>>>(f, proposals, out);
}

// Round 2
// 217.790 us; speedup vs baseline: 1.0111x; 1.0111x over previous
//
#include <hip/hip_runtime.h>
#include <math.h>

// CropRoi via block-per-(n, channel-pair) LDS staging.
// f:         (B=2, C=128, 32, 64, 64) float32
// proposals: (N=32, 8) float32 = [b, score, cz, cy, cx, sz, sy, sx]
// out:       (N=32, C=128, 7, 7, 7) float32
//
// Reference semantics:
//   c0 = max(floor((center - side/2)/4), 0); c1 = min(ceil((center + side/2)/4), dim)
//   L = c1 - c0  (always >= 4 since side >= 16 and boxes are interior)
//   window i = [i*L//7, ceil((i+1)*L/7))  relative to c0; width <= 4; never empty.
//
// Staging trick: load a FIXED 17x17x17 region per channel with indices clamped
// to the valid crop (min(z,Lz-1) etc). Duplicated elements are harmless under
// max-pooling, and fixed compile-time LDS strides avoid runtime int division.

constexpr int C_CH = 128;
constexpr int FD = 32, FH = 64, FW = 64;
constexpr int CH_VOL = FD * FH * FW;        // 131072
constexpr int LMAX = 17;                    // max crop extent: 64/4 + 1
constexpr int VOL = LMAX * LMAX * LMAX;     // 4913
constexpr int CPB = 2;                      // channels per block
constexpr int THREADS = 256;

__global__ __launch_bounds__(THREADS) void crop_roi_kernel(
    const float* __restrict__ f,
    const float* __restrict__ proposals,
    float* __restrict__ out)
{
    __shared__ float lds[CPB * VOL];        // 39316 B

    const int n    = blockIdx.x;            // proposal
    const int c0ch = blockIdx.y * CPB;      // first channel of this block

    const float* p = proposals + n * 8;
    const int   b  = (int)p[0];
    const float cz = p[2], cy = p[3], cx = p[4];
    const float sz = p[5], sy = p[6], sx = p[7];

    const int c0z = max((int)floorf((cz - sz * 0.5f) * 0.25f), 0);
    const int c0y = max((int)floorf((cy - sy * 0.5f) * 0.25f), 0);
    const int c0x = max((int)floorf((cx - sx * 0.5f) * 0.25f), 0);
    const int c1z = min((int)ceilf((cz + sz * 0.5f) * 0.25f), FD);
    const int c1y = min((int)ceilf((cy + sy * 0.5f) * 0.25f), FH);
    const int c1x = min((int)ceilf((cx + sx * 0.5f) * 0.25f), FW);
    const int Lz = c1z - c0z, Ly = c1y - c0y, Lx = c1x - c0x;

    // ---- stage clamped 17^3 crop per channel into LDS (coalesced-ish, high ILP)
    const float* fb = f + (size_t)(b * C_CH + c0ch) * CH_VOL
                        + c0z * (FH * FW) + c0y * FW + c0x;
    #pragma unroll 4
    for (int e = threadIdx.x; e < CPB * VOL; e += THREADS) {
        int cl = e / VOL;
        int r  = e % VOL;                   // compile-time divisors -> magic mul
        int z  = r / (LMAX * LMAX);
        int y  = (r / LMAX) % LMAX;
        int x  = r % LMAX;
        int zc = min(z, Lz - 1);
        int yc = min(y, Ly - 1);
        int xc = min(x, Lx - 1);
        lds[e] = fb[(size_t)cl * CH_VOL + zc * (FH * FW) + yc * FW + xc];
    }
    __syncthreads();

    // ---- pool 7x7x7 per channel from LDS
    for (int o = threadIdx.x; o < CPB * 343; o += THREADS) {
        int cl = o / 343;
        int r  = o % 343;
        int iz = r / 49, iy = (r / 7) % 7, ix = r % 7;

        int zs = (iz * Lz) / 7, ze = ((iz + 1) * Lz + 6) / 7;
        int ys = (iy * Ly) / 7, ye = ((iy + 1) * Ly + 6) / 7;
        int xs = (ix * Lx) / 7, xe = ((ix + 1) * Lx + 6) / 7;

        const float* Lp = lds + cl * VOL;
        float m = -INFINITY;
        for (int z = zs; z < ze; ++z) {
            for (int y = ys; y < ye; ++y) {
                int base = z * (LMAX * LMAX) + y * LMAX;
                // x-window width in [1,4]; clamped unroll (duplicates OK for max)
                int xm = xe - 1;
                float v0 = Lp[base + xs];
                float v1 = Lp[base + min(xs + 1, xm)];
                float v2 = Lp[base + min(xs + 2, xm)];
                float v3 = Lp[base + min(xs + 3, xm)];
                m = fmaxf(m, fmaxf(fmaxf(v0, v1), fmaxf(v2, v3)));
            }
        }
        out[(size_t)(n * C_CH + c0ch) * 343 + o] = m;   // contiguous per block
    }
}

extern "C" void kernel_launch(void* const* d_in, const int* in_sizes, int n_in,
                              void* d_out, int out_size, void* d_ws, size_t ws_size,
                              hipStream_t stream) {
    const float* f         = (const float*)d_in[0];
    // d_in[1] = `inputs` zeros tensor — shape-only in the reference; unused.
    const float* proposals = (const float*)d_in[2];
    float* out             = (float*)d_out;

    dim3 grid(32, C_CH / CPB);   // 32 proposals x 64 channel-pairs = 2048 blocks
    crop_roi_kernel<<<grid, THREADS, 0, stream>>>(f, proposals, out);
}